// Round 3
// baseline (1544.525 us; speedup 1.0000x reference)
//
#include <hip/hip_runtime.h>
#include <cstdint>

typedef unsigned long long u64;

#define TPB 256

static __device__ __forceinline__ u64 rfl64(u64 x) {
    unsigned lo = __builtin_amdgcn_readfirstlane((unsigned)x);
    unsigned hi = __builtin_amdgcn_readfirstlane((unsigned)(x >> 32));
    return ((u64)hi << 32) | (u64)lo;
}

// ---------------------------------------------------------------------------
// gamma^dist table, fp64. pw[h*512 + dist]
__global__ void pow_kernel(double* __restrict__ pw) {
    int h = threadIdx.x;
    if (h < 8) {
        double gamma = 1.0 - ldexp(1.0, -5 - h);   // 1 - 2^-(5+h), exact
        double p = 1.0;
        for (int i = 0; i < 512; ++i) { pw[h * 512 + i] = p; p *= gamma; }
    }
}

// ---------------------------------------------------------------------------
// out[m,d] = BN( sum_c A[m,c]*W[d,c] + bias[d] ), fp64 accumulation.
__global__ __launch_bounds__(256) void gemm_bn(
    const float* __restrict__ A, const float* __restrict__ W,
    const float* __restrict__ bias,
    const float* __restrict__ bnw, const float* __restrict__ bnb,
    const float* __restrict__ bnm, const float* __restrict__ bnv,
    float* __restrict__ out)
{
    const int K = 512;
    __shared__ float As[64][36];
    __shared__ float Ws[64][36];

    const int tid = threadIdx.x;
    const int m0 = blockIdx.x * 64;
    const int d0 = blockIdx.y * 64;
    const int lr = tid >> 3;
    const int lc = (tid & 7) << 2;
    const int tm = tid >> 4;
    const int td = tid & 15;

    double acc[4][4];
    #pragma unroll
    for (int i = 0; i < 4; ++i)
        #pragma unroll
        for (int j = 0; j < 4; ++j) acc[i][j] = 0.0;

    for (int k0 = 0; k0 < K; k0 += 32) {
        float4 a0 = *(const float4*)(A + (size_t)(m0 + lr) * K + k0 + lc);
        float4 a1 = *(const float4*)(A + (size_t)(m0 + lr + 32) * K + k0 + lc);
        float4 w0 = *(const float4*)(W + (size_t)(d0 + lr) * K + k0 + lc);
        float4 w1 = *(const float4*)(W + (size_t)(d0 + lr + 32) * K + k0 + lc);
        __syncthreads();
        *(float4*)&As[lr][lc]      = a0;
        *(float4*)&As[lr + 32][lc] = a1;
        *(float4*)&Ws[lr][lc]      = w0;
        *(float4*)&Ws[lr + 32][lc] = w1;
        __syncthreads();
        #pragma unroll 8
        for (int kk = 0; kk < 32; ++kk) {
            double av[4], wv[4];
            #pragma unroll
            for (int i = 0; i < 4; ++i) av[i] = (double)As[tm + 16 * i][kk];
            #pragma unroll
            for (int j = 0; j < 4; ++j) wv[j] = (double)Ws[td + 16 * j][kk];
            #pragma unroll
            for (int i = 0; i < 4; ++i)
                #pragma unroll
                for (int j = 0; j < 4; ++j)
                    acc[i][j] += av[i] * wv[j];
        }
    }

    #pragma unroll
    for (int j = 0; j < 4; ++j) {
        int d = d0 + td + 16 * j;
        double inv = (double)bnw[d] / sqrt((double)bnv[d] + 1e-5);
        double sh  = (double)bnb[d] - (double)bnm[d] * inv;
        double bs  = (double)bias[d];
        #pragma unroll
        for (int i = 0; i < 4; ++i) {
            int m = m0 + tm + 16 * i;
            out[(size_t)m * 512 + d] = (float)((acc[i][j] + bs) * inv + sh);
        }
    }
}

// ---------------------------------------------------------------------------
// LIF (v_th=1.0) over T=4 on Y; pack spikes into per-(t,b,h,n) 64-bit masks.
__global__ void lif_mask(const float* __restrict__ Y, u64* __restrict__ msk) {
    int g = blockIdx.x * TPB + threadIdx.x;
    int c = g & 511, n = (g >> 9) & 511, b = g >> 18;
    int h = c >> 6;
    int lane = threadIdx.x & 63;
    double v = 0.0;
    for (int t = 0; t < 4; ++t) {
        float y = Y[((size_t)((t * 8 + b) * 512 + n) << 9) + c];
        double hh = v + ((double)y - v) * 0.5;
        bool s = hh >= 1.0;
        u64 mk = __ballot(s);
        if (lane == 0) msk[((t * 8 + b) * 8 + h) * 512 + n] = mk;
        v = s ? 0.0 : hh;
    }
}

// ---------------------------------------------------------------------------
// Retention + retention LIF, v3.
// Block = 512 threads = 8 waves = t(4) x dhalf(2), one (b,h,ngroup).
// lane = n (64 rows). acc[32] fp64 per wave (d-half) keeps regs ~90.
// k/v masks for all 4 t staged in LDS once (32 KB), read as uniform
// broadcasts + readfirstlane -> SGPR; d-gating runs on SALU.
// LIF vstate chained t-wave -> t-wave through the SAME LDS (reused after
// a barrier), XOR-swizzled to kill bank conflicts.
__global__ __launch_bounds__(512) void retention3(
    const u64* __restrict__ qm, const u64* __restrict__ km,
    const u64* __restrict__ vm, const double* __restrict__ pw,
    float* __restrict__ r)
{
    int bid = blockIdx.x;            // 512 = b(8) * h(8) * ng(8)
    int ng = bid & 7;
    int h  = (bid >> 3) & 7;
    int b  = bid >> 6;
    int wid  = threadIdx.x >> 6;     // 0..7
    int t    = wid >> 1;             // 0..3
    int dh   = wid & 1;              // 0..1
    int lane = threadIdx.x & 63;
    int n = ng * 64 + lane;

    __shared__ double pw_s[512];              // 4 KB
    __shared__ u64 stage[4][2][512];          // 32 KB: [t][k|v][m]; reused as vstate
    double* vs_s = (double*)stage;            // 4096 doubles

    for (int i = threadIdx.x; i < 512; i += 512) pw_s[i] = pw[h * 512 + i];
    for (int i = threadIdx.x; i < 2048; i += 512) {
        int tt = i >> 9, mm = i & 511;
        int gbase = ((tt * 8 + b) * 8 + h) * 512 + mm;
        stage[tt][0][mm] = km[gbase];
        stage[tt][1][mm] = vm[gbase];
    }
    __syncthreads();

    int base = ((t * 8 + b) * 8 + h) * 512;
    u64 qn = qm[base + n];

    double acc[32];
    #pragma unroll
    for (int dd = 0; dd < 32; ++dd) acc[dd] = 0.0;

    #pragma unroll 2
    for (int m = 0; m < 512; ++m) {
        u64 kv = rfl64(stage[t][0][m]);   // uniform LDS broadcast -> SGPR
        u64 vv = rfl64(stage[t][1][m]);
        int dist = n - m; if (dist < 0) dist = -dist;
        double w = (double)__popcll(qn & kv) * pw_s[dist];
        #pragma unroll
        for (int dd = 0; dd < 32; ++dd) {
            int d = dh * 32 + dd;
            acc[dd] = fma(w, ((vv >> d) & 1ULL) ? 1.0 : 0.0, acc[dd]);
        }
    }

    __syncthreads();   // staging reads done; stage[] now reused as vstate
    for (int tt = 0; tt < 4; ++tt) {
        if (tt == t) {
            size_t rbase = ((size_t)((t * 8 + b) * 512 + n) << 9) + h * 64 + dh * 32;
            #pragma unroll
            for (int dd = 0; dd < 32; ++dd) {
                int d = dh * 32 + dd;
                double v = (t == 0) ? 0.0 : vs_s[lane * 64 + (d ^ lane)];
                double x = acc[dd] * 0.125;
                double hh = v + (x - v) * 0.5;
                bool s = hh >= 0.5;
                r[rbase + dd] = s ? 1.0f : 0.0f;
                if (t < 3) vs_s[lane * 64 + (d ^ lane)] = s ? 0.0 : hh;
            }
        }
        __syncthreads();
    }
}

// ---------------------------------------------------------------------------
// Final LIF (v_th=1.0) over T on Y; writes {0,1} fp32 to out.
__global__ void final_lif(const float* __restrict__ Y, float* __restrict__ out) {
    int g = blockIdx.x * TPB + threadIdx.x;
    int c = g & 511, n = (g >> 9) & 511, b = g >> 18;
    double v = 0.0;
    for (int t = 0; t < 4; ++t) {
        size_t idx = ((size_t)((t * 8 + b) * 512 + n) << 9) + c;
        float y = Y[idx];
        double hh = v + ((double)y - v) * 0.5;
        bool s = hh >= 1.0;
        out[idx] = s ? 1.0f : 0.0f;
        v = s ? 0.0 : hh;
    }
}

// ---------------------------------------------------------------------------
extern "C" void kernel_launch(void* const* d_in, const int* in_sizes, int n_in,
                              void* d_out, int out_size, void* d_ws, size_t ws_size,
                              hipStream_t stream) {
    const float* x = (const float*)d_in[0];
    const float *w[4], *bi[4], *bnw[4], *bnb[4], *bnm[4], *bnv[4];
    for (int br = 0; br < 4; ++br) {
        int base = 1 + br * 6;
        w[br]   = (const float*)d_in[base + 0];
        bi[br]  = (const float*)d_in[base + 1];
        bnw[br] = (const float*)d_in[base + 2];
        bnb[br] = (const float*)d_in[base + 3];
        bnm[br] = (const float*)d_in[base + 4];
        bnv[br] = (const float*)d_in[base + 5];
    }

    char* p = (char*)d_ws;
    double* pw = (double*)p;  p += 8 * 512 * sizeof(double);      // 32 KB
    u64* qm = (u64*)p;        p += 131072 * sizeof(u64);          // 1 MB
    u64* km = (u64*)p;        p += 131072 * sizeof(u64);          // 1 MB
    u64* vm = (u64*)p;        p += 131072 * sizeof(u64);          // 1 MB
    float* Y = (float*)p;     p += (size_t)16384 * 512 * 4;       // 33.5 MB
    float* r = (float*)d_out;  // retention spikes staged in d_out, consumed
                               // by the p-GEMM, then d_out fully rewritten.

    pow_kernel<<<1, 64, 0, stream>>>(pw);

    dim3 gg(256, 8);
    gemm_bn<<<gg, 256, 0, stream>>>(x, w[0], bi[0], bnw[0], bnb[0], bnm[0], bnv[0], Y);
    lif_mask<<<8192, TPB, 0, stream>>>(Y, qm);
    gemm_bn<<<gg, 256, 0, stream>>>(x, w[1], bi[1], bnw[1], bnb[1], bnm[1], bnv[1], Y);
    lif_mask<<<8192, TPB, 0, stream>>>(Y, km);
    gemm_bn<<<gg, 256, 0, stream>>>(x, w[2], bi[2], bnw[2], bnb[2], bnm[2], bnv[2], Y);
    lif_mask<<<8192, TPB, 0, stream>>>(Y, vm);

    retention3<<<512, 512, 0, stream>>>(qm, km, vm, pw, r);

    gemm_bn<<<gg, 256, 0, stream>>>(r, w[3], bi[3], bnw[3], bnb[3], bnm[3], bnv[3], Y);
    final_lif<<<8192, TPB, 0, stream>>>(Y, (float*)d_out);
}

// Round 4
// 1282.414 us; speedup vs baseline: 1.2044x; 1.2044x over previous
//
#include <hip/hip_runtime.h>
#include <cstdint>

typedef unsigned long long u64;

#define TPB 256

// ---------------------------------------------------------------------------
// gamma^dist table, fp64. pw[h*512 + dist]
__global__ void pow_kernel(double* __restrict__ pw) {
    int h = threadIdx.x;
    if (h < 8) {
        double gamma = 1.0 - ldexp(1.0, -5 - h);   // 1 - 2^-(5+h), exact
        double p = 1.0;
        for (int i = 0; i < 512; ++i) { pw[h * 512 + i] = p; p *= gamma; }
    }
}

// ---------------------------------------------------------------------------
// out[m,d] = BN( sum_c A[m,c]*W[d,c] + bias[d] ), fp64 accumulation.
__global__ __launch_bounds__(256) void gemm_bn(
    const float* __restrict__ A, const float* __restrict__ W,
    const float* __restrict__ bias,
    const float* __restrict__ bnw, const float* __restrict__ bnb,
    const float* __restrict__ bnm, const float* __restrict__ bnv,
    float* __restrict__ out)
{
    const int K = 512;
    __shared__ float As[64][36];
    __shared__ float Ws[64][36];

    const int tid = threadIdx.x;
    const int m0 = blockIdx.x * 64;
    const int d0 = blockIdx.y * 64;
    const int lr = tid >> 3;
    const int lc = (tid & 7) << 2;
    const int tm = tid >> 4;
    const int td = tid & 15;

    double acc[4][4];
    #pragma unroll
    for (int i = 0; i < 4; ++i)
        #pragma unroll
        for (int j = 0; j < 4; ++j) acc[i][j] = 0.0;

    for (int k0 = 0; k0 < K; k0 += 32) {
        float4 a0 = *(const float4*)(A + (size_t)(m0 + lr) * K + k0 + lc);
        float4 a1 = *(const float4*)(A + (size_t)(m0 + lr + 32) * K + k0 + lc);
        float4 w0 = *(const float4*)(W + (size_t)(d0 + lr) * K + k0 + lc);
        float4 w1 = *(const float4*)(W + (size_t)(d0 + lr + 32) * K + k0 + lc);
        __syncthreads();
        *(float4*)&As[lr][lc]      = a0;
        *(float4*)&As[lr + 32][lc] = a1;
        *(float4*)&Ws[lr][lc]      = w0;
        *(float4*)&Ws[lr + 32][lc] = w1;
        __syncthreads();
        #pragma unroll 8
        for (int kk = 0; kk < 32; ++kk) {
            double av[4], wv[4];
            #pragma unroll
            for (int i = 0; i < 4; ++i) av[i] = (double)As[tm + 16 * i][kk];
            #pragma unroll
            for (int j = 0; j < 4; ++j) wv[j] = (double)Ws[td + 16 * j][kk];
            #pragma unroll
            for (int i = 0; i < 4; ++i)
                #pragma unroll
                for (int j = 0; j < 4; ++j)
                    acc[i][j] += av[i] * wv[j];
        }
    }

    #pragma unroll
    for (int j = 0; j < 4; ++j) {
        int d = d0 + td + 16 * j;
        double inv = (double)bnw[d] / sqrt((double)bnv[d] + 1e-5);
        double sh  = (double)bnb[d] - (double)bnm[d] * inv;
        double bs  = (double)bias[d];
        #pragma unroll
        for (int i = 0; i < 4; ++i) {
            int m = m0 + tm + 16 * i;
            out[(size_t)m * 512 + d] = (float)((acc[i][j] + bs) * inv + sh);
        }
    }
}

// ---------------------------------------------------------------------------
// LIF (v_th=1.0) over T=4 on Y; pack spikes into per-(t,b,h,n) 64-bit masks.
__global__ void lif_mask(const float* __restrict__ Y, u64* __restrict__ msk) {
    int g = blockIdx.x * TPB + threadIdx.x;
    int c = g & 511, n = (g >> 9) & 511, b = g >> 18;
    int h = c >> 6;
    int lane = threadIdx.x & 63;
    double v = 0.0;
    for (int t = 0; t < 4; ++t) {
        float y = Y[((size_t)((t * 8 + b) * 512 + n) << 9) + c];
        double hh = v + ((double)y - v) * 0.5;
        bool s = hh >= 1.0;
        u64 mk = __ballot(s);
        if (lane == 0) msk[((t * 8 + b) * 8 + h) * 512 + n] = mk;
        v = s ? 0.0 : hh;
    }
}

// ---------------------------------------------------------------------------
// Retention + retention LIF, v4.
// Grid = 1024 blocks = b(8) x h(8) x ng(8) x dhalf(2); block = 256 = 4 t-waves.
// lane = n (64 rows/wave); acc[32] fp64 = this block's d-half.
// k/v masks: each lane loads a DIFFERENT m (coalesced, double-buffered one
// 64-m chunk ahead); inner loop broadcasts via v_readlane -> SGPR, so the
// per-d gating stays on SALU (s_lshr/s_cselect) under the fp64 FMAs.
// LIF vstate chained t-wave -> t-wave through XOR-swizzled LDS.
__global__ __launch_bounds__(256) void retention4(
    const u64* __restrict__ qm, const u64* __restrict__ km,
    const u64* __restrict__ vm, const double* __restrict__ pw,
    float* __restrict__ r)
{
    int bid = blockIdx.x;            // 1024 = b(8)*h(8)*ng(8)*dh(2)
    int dh = bid & 1;
    int ng = (bid >> 1) & 7;
    int h  = (bid >> 4) & 7;
    int b  = bid >> 7;
    int t    = threadIdx.x >> 6;     // wave id == time step
    int lane = threadIdx.x & 63;
    int n = ng * 64 + lane;

    __shared__ double pw_s[512];      // 4 KB
    __shared__ double vs_s[64 * 32];  // 16 KB vstate hand-off

    for (int i = threadIdx.x; i < 512; i += 256) pw_s[i] = pw[h * 512 + i];
    __syncthreads();

    int base = ((t * 8 + b) * 8 + h) * 512;
    u64 qn = qm[base + n];
    const u64* kp = km + base;
    const u64* vp = vm + base;

    double acc[32];
    #pragma unroll
    for (int dd = 0; dd < 32; ++dd) acc[dd] = 0.0;

    u64 kcur = kp[lane];
    u64 vcur = vp[lane];
    #pragma unroll 1
    for (int c = 0; c < 8; ++c) {
        u64 knxt = 0, vnxt = 0;
        if (c < 7) {
            knxt = kp[(c + 1) * 64 + lane];
            vnxt = vp[(c + 1) * 64 + lane];
        }
        int mbase = c * 64;
        #pragma unroll 2
        for (int mm = 0; mm < 64; ++mm) {
            unsigned kl = __builtin_amdgcn_readlane((unsigned)kcur, mm);
            unsigned kh = __builtin_amdgcn_readlane((unsigned)(kcur >> 32), mm);
            unsigned vl = __builtin_amdgcn_readlane((unsigned)vcur, mm);
            unsigned vh = __builtin_amdgcn_readlane((unsigned)(vcur >> 32), mm);
            u64 kv = ((u64)kh << 32) | kl;
            u64 vv = ((u64)vh << 32) | vl;
            int m = mbase + mm;
            int dist = n - m; if (dist < 0) dist = -dist;
            double w = (double)__popcll(qn & kv) * pw_s[dist];
            #pragma unroll
            for (int dd = 0; dd < 32; ++dd) {
                int d = dh * 32 + dd;
                acc[dd] = fma(w, ((vv >> d) & 1ULL) ? 1.0 : 0.0, acc[dd]);
            }
        }
        kcur = knxt; vcur = vnxt;
    }

    __syncthreads();
    // LIF chain across the 4 t-waves, v_th = 0.5, hard reset
    for (int tt = 0; tt < 4; ++tt) {
        if (tt == t) {
            size_t rbase = ((size_t)((t * 8 + b) * 512 + n) << 9) + h * 64 + dh * 32;
            #pragma unroll
            for (int dd = 0; dd < 32; ++dd) {
                int sw = lane * 32 + (dd ^ (lane & 31));
                double v = (t == 0) ? 0.0 : vs_s[sw];
                double x = acc[dd] * 0.125;
                double hh = v + (x - v) * 0.5;
                bool s = hh >= 0.5;
                r[rbase + dd] = s ? 1.0f : 0.0f;
                if (t < 3) vs_s[sw] = s ? 0.0 : hh;
            }
        }
        __syncthreads();
    }
}

// ---------------------------------------------------------------------------
// Final LIF (v_th=1.0) over T on Y; writes {0,1} fp32 to out.
__global__ void final_lif(const float* __restrict__ Y, float* __restrict__ out) {
    int g = blockIdx.x * TPB + threadIdx.x;
    int c = g & 511, n = (g >> 9) & 511, b = g >> 18;
    double v = 0.0;
    for (int t = 0; t < 4; ++t) {
        size_t idx = ((size_t)((t * 8 + b) * 512 + n) << 9) + c;
        float y = Y[idx];
        double hh = v + ((double)y - v) * 0.5;
        bool s = hh >= 1.0;
        out[idx] = s ? 1.0f : 0.0f;
        v = s ? 0.0 : hh;
    }
}

// ---------------------------------------------------------------------------
extern "C" void kernel_launch(void* const* d_in, const int* in_sizes, int n_in,
                              void* d_out, int out_size, void* d_ws, size_t ws_size,
                              hipStream_t stream) {
    const float* x = (const float*)d_in[0];
    const float *w[4], *bi[4], *bnw[4], *bnb[4], *bnm[4], *bnv[4];
    for (int br = 0; br < 4; ++br) {
        int base = 1 + br * 6;
        w[br]   = (const float*)d_in[base + 0];
        bi[br]  = (const float*)d_in[base + 1];
        bnw[br] = (const float*)d_in[base + 2];
        bnb[br] = (const float*)d_in[base + 3];
        bnm[br] = (const float*)d_in[base + 4];
        bnv[br] = (const float*)d_in[base + 5];
    }

    char* p = (char*)d_ws;
    double* pw = (double*)p;  p += 8 * 512 * sizeof(double);      // 32 KB
    u64* qm = (u64*)p;        p += 131072 * sizeof(u64);          // 1 MB
    u64* km = (u64*)p;        p += 131072 * sizeof(u64);          // 1 MB
    u64* vm = (u64*)p;        p += 131072 * sizeof(u64);          // 1 MB
    float* Y = (float*)p;     p += (size_t)16384 * 512 * 4;       // 33.5 MB
    float* r = (float*)d_out;  // retention spikes staged in d_out, consumed
                               // by the p-GEMM, then d_out fully rewritten.

    pow_kernel<<<1, 64, 0, stream>>>(pw);

    dim3 gg(256, 8);
    gemm_bn<<<gg, 256, 0, stream>>>(x, w[0], bi[0], bnw[0], bnb[0], bnm[0], bnv[0], Y);
    lif_mask<<<8192, TPB, 0, stream>>>(Y, qm);
    gemm_bn<<<gg, 256, 0, stream>>>(x, w[1], bi[1], bnw[1], bnb[1], bnm[1], bnv[1], Y);
    lif_mask<<<8192, TPB, 0, stream>>>(Y, km);
    gemm_bn<<<gg, 256, 0, stream>>>(x, w[2], bi[2], bnw[2], bnb[2], bnm[2], bnv[2], Y);
    lif_mask<<<8192, TPB, 0, stream>>>(Y, vm);

    retention4<<<1024, TPB, 0, stream>>>(qm, km, vm, pw, r);

    gemm_bn<<<gg, 256, 0, stream>>>(r, w[3], bi[3], bnw[3], bnb[3], bnm[3], bnv[3], Y);
    final_lif<<<8192, TPB, 0, stream>>>(Y, (float*)d_out);
}

// Round 6
// 1202.728 us; speedup vs baseline: 1.2842x; 1.0663x over previous
//
#include <hip/hip_runtime.h>
#include <cstdint>

typedef unsigned long long u64;

#define TPB 256

// ---------------------------------------------------------------------------
// gamma^dist table, fp64. pw[h*512 + dist]
__global__ void pow_kernel(double* __restrict__ pw) {
    int h = threadIdx.x;
    if (h < 8) {
        double gamma = 1.0 - ldexp(1.0, -5 - h);   // 1 - 2^-(5+h), exact
        double p = 1.0;
        for (int i = 0; i < 512; ++i) { pw[h * 512 + i] = p; p *= gamma; }
    }
}

// ---------------------------------------------------------------------------
// out[m,d] = BN( sum_c A[m,c]*W[d,c] + bias[d] ), fp64 accumulation.
__global__ __launch_bounds__(256) void gemm_bn(
    const float* __restrict__ A, const float* __restrict__ W,
    const float* __restrict__ bias,
    const float* __restrict__ bnw, const float* __restrict__ bnb,
    const float* __restrict__ bnm, const float* __restrict__ bnv,
    float* __restrict__ out)
{
    const int K = 512;
    __shared__ float As[64][36];
    __shared__ float Ws[64][36];

    const int tid = threadIdx.x;
    const int m0 = blockIdx.x * 64;
    const int d0 = blockIdx.y * 64;
    const int lr = tid >> 3;
    const int lc = (tid & 7) << 2;
    const int tm = tid >> 4;
    const int td = tid & 15;

    double acc[4][4];
    #pragma unroll
    for (int i = 0; i < 4; ++i)
        #pragma unroll
        for (int j = 0; j < 4; ++j) acc[i][j] = 0.0;

    for (int k0 = 0; k0 < K; k0 += 32) {
        float4 a0 = *(const float4*)(A + (size_t)(m0 + lr) * K + k0 + lc);
        float4 a1 = *(const float4*)(A + (size_t)(m0 + lr + 32) * K + k0 + lc);
        float4 w0 = *(const float4*)(W + (size_t)(d0 + lr) * K + k0 + lc);
        float4 w1 = *(const float4*)(W + (size_t)(d0 + lr + 32) * K + k0 + lc);
        __syncthreads();
        *(float4*)&As[lr][lc]      = a0;
        *(float4*)&As[lr + 32][lc] = a1;
        *(float4*)&Ws[lr][lc]      = w0;
        *(float4*)&Ws[lr + 32][lc] = w1;
        __syncthreads();
        #pragma unroll 8
        for (int kk = 0; kk < 32; ++kk) {
            double av[4], wv[4];
            #pragma unroll
            for (int i = 0; i < 4; ++i) av[i] = (double)As[tm + 16 * i][kk];
            #pragma unroll
            for (int j = 0; j < 4; ++j) wv[j] = (double)Ws[td + 16 * j][kk];
            #pragma unroll
            for (int i = 0; i < 4; ++i)
                #pragma unroll
                for (int j = 0; j < 4; ++j)
                    acc[i][j] += av[i] * wv[j];
        }
    }

    #pragma unroll
    for (int j = 0; j < 4; ++j) {
        int d = d0 + td + 16 * j;
        double inv = (double)bnw[d] / sqrt((double)bnv[d] + 1e-5);
        double sh  = (double)bnb[d] - (double)bnm[d] * inv;
        double bs  = (double)bias[d];
        #pragma unroll
        for (int i = 0; i < 4; ++i) {
            int m = m0 + tm + 16 * i;
            out[(size_t)m * 512 + d] = (float)((acc[i][j] + bs) * inv + sh);
        }
    }
}

// ---------------------------------------------------------------------------
// LIF (v_th=1.0) over T=4 on Y; pack spikes into per-(t,b,h,n) 64-bit masks.
__global__ void lif_mask(const float* __restrict__ Y, u64* __restrict__ msk) {
    int g = blockIdx.x * TPB + threadIdx.x;
    int c = g & 511, n = (g >> 9) & 511, b = g >> 18;
    int h = c >> 6;
    int lane = threadIdx.x & 63;
    double v = 0.0;
    for (int t = 0; t < 4; ++t) {
        float y = Y[((size_t)((t * 8 + b) * 512 + n) << 9) + c];
        double hh = v + ((double)y - v) * 0.5;
        bool s = hh >= 1.0;
        u64 mk = __ballot(s);
        if (lane == 0) msk[((t * 8 + b) * 8 + h) * 512 + n] = mk;
        v = s ? 0.0 : hh;
    }
}

// ---------------------------------------------------------------------------
// Retention + retention LIF, v5.
// Grid 1024 = b(8)*h(8)*ng(8)*dh(2); block 512 = 8 waves = t(4) x mhalf(2).
// lane = n; acc[32] fp64 = this block's d-half; each wave sums 256 m's.
// Gating mix: 14 d's via pure-VALU sext-mask (laundered VGPR, 0 SALU),
// 18 d's via s_cselect+v_fma_f64 (2 SALU) -> SALU demand < 1/cy/CU.
// m-half partials combined in LDS (fixed-order fp64, deterministic),
// then LIF chained across t-waves through reused LDS.
#define NMASK 14
__global__ __launch_bounds__(512) void retention5(
    const u64* __restrict__ qm, const u64* __restrict__ km,
    const u64* __restrict__ vm, const double* __restrict__ pw,
    float* __restrict__ r)
{
    int bid = blockIdx.x;            // 1024 = b(8)*h(8)*ng(8)*dh(2)
    int dh = bid & 1;
    int ng = (bid >> 1) & 7;
    int h  = (bid >> 4) & 7;
    int b  = bid >> 7;
    int wid  = threadIdx.x >> 6;     // 0..7
    int t    = wid & 3;
    int mh   = wid >> 2;             // m-half
    int lane = threadIdx.x & 63;
    int n = ng * 64 + lane;

    __shared__ double pw_s[512];            // 4 KB
    __shared__ double comb[4][64][17];      // 34 KB combine buffer (padded)
    double* vs_s = &comb[0][0][0];          // reused for LIF vstate

    if (threadIdx.x < 512) pw_s[threadIdx.x] = pw[h * 512 + threadIdx.x];
    __syncthreads();

    int base = ((t * 8 + b) * 8 + h) * 512;
    u64 qn = qm[base + n];
    const u64* kp = km + base + mh * 256;
    const u64* vp = vm + base + mh * 256;
    int msta = mh * 256;

    double acc[32];
    #pragma unroll
    for (int dd = 0; dd < 32; ++dd) acc[dd] = 0.0;

    u64 kcur = kp[lane];
    u64 vcur = vp[lane];
    #pragma unroll 1
    for (int c = 0; c < 4; ++c) {
        u64 knxt = 0, vnxt = 0;
        if (c < 3) {
            knxt = kp[(c + 1) * 64 + lane];
            vnxt = vp[(c + 1) * 64 + lane];
        }
        // the 32 v-bits this block needs live in one 32-bit word (dh picks it)
        unsigned vsel = dh ? (unsigned)(vcur >> 32) : (unsigned)vcur;
        int mbase = msta + c * 64;
        #pragma unroll 2
        for (int mm = 0; mm < 64; ++mm) {
            unsigned kl = __builtin_amdgcn_readlane((unsigned)kcur, mm);
            unsigned kh = __builtin_amdgcn_readlane((unsigned)(kcur >> 32), mm);
            unsigned vv_s = __builtin_amdgcn_readlane(vsel, mm);   // SGPR
            u64 kv = ((u64)kh << 32) | kl;
            int m = mbase + mm;
            int dist = n - m; if (dist < 0) dist = -dist;
            double w = (double)__popcll(qn & kv) * pw_s[dist];
            u64 wbits = __builtin_bit_cast(u64, w);

            // VALU-mask path: launder vv into a VGPR so it can't scalarize
            unsigned vv_v;
            asm("v_mov_b32 %0, %1" : "=v"(vv_v) : "s"(vv_s));
            #pragma unroll
            for (int dd = 0; dd < NMASK; ++dd) {
                unsigned mk = (unsigned)(((int)(vv_v << (31 - dd))) >> 31);
                u64 gw = (((u64)mk << 32) | mk) & wbits;
                acc[dd] += __builtin_bit_cast(double, gw);
            }
            // SALU-select path
            #pragma unroll
            for (int dd = NMASK; dd < 32; ++dd)
                acc[dd] = fma(w, ((vv_s >> dd) & 1u) ? 1.0 : 0.0, acc[dd]);
        }
        kcur = knxt; vcur = vnxt;
    }

    // ---- combine m-halves (fixed order: acc(mh0) + acc(mh1)), 16 d at a time
    __syncthreads();
    if (mh == 1) {
        #pragma unroll
        for (int dd = 0; dd < 16; ++dd) comb[t][lane][dd] = acc[dd];
    }
    __syncthreads();
    if (mh == 0) {
        #pragma unroll
        for (int dd = 0; dd < 16; ++dd) acc[dd] += comb[t][lane][dd];
    }
    __syncthreads();
    if (mh == 1) {
        #pragma unroll
        for (int dd = 16; dd < 32; ++dd) comb[t][lane][dd - 16] = acc[dd];
    }
    __syncthreads();
    if (mh == 0) {
        #pragma unroll
        for (int dd = 16; dd < 32; ++dd) acc[dd] += comb[t][lane][dd - 16];
    }
    __syncthreads();

    // ---- LIF chain across t (v_th=0.5, hard reset); vstate via reused LDS
    for (int tt = 0; tt < 4; ++tt) {
        if (tt == t && mh == 0) {
            size_t rbase = ((size_t)((t * 8 + b) * 512 + n) << 9) + h * 64 + dh * 32;
            #pragma unroll
            for (int dd = 0; dd < 32; ++dd) {
                int sw = lane * 33 + dd;
                double v = (t == 0) ? 0.0 : vs_s[sw];
                double x = acc[dd] * 0.125;
                double hh = v + (x - v) * 0.5;
                bool s = hh >= 0.5;
                r[rbase + dd] = s ? 1.0f : 0.0f;
                if (t < 3) vs_s[sw] = s ? 0.0 : hh;
            }
        }
        __syncthreads();
    }
}

// ---------------------------------------------------------------------------
// Final LIF (v_th=1.0) over T on Y; writes {0,1} fp32 to out.
__global__ void final_lif(const float* __restrict__ Y, float* __restrict__ out) {
    int g = blockIdx.x * TPB + threadIdx.x;
    int c = g & 511, n = (g >> 9) & 511, b = g >> 18;
    double v = 0.0;
    for (int t = 0; t < 4; ++t) {
        size_t idx = ((size_t)((t * 8 + b) * 512 + n) << 9) + c;
        float y = Y[idx];
        double hh = v + ((double)y - v) * 0.5;
        bool s = hh >= 1.0;
        out[idx] = s ? 1.0f : 0.0f;
        v = s ? 0.0 : hh;
    }
}

// ---------------------------------------------------------------------------
extern "C" void kernel_launch(void* const* d_in, const int* in_sizes, int n_in,
                              void* d_out, int out_size, void* d_ws, size_t ws_size,
                              hipStream_t stream) {
    const float* x = (const float*)d_in[0];
    const float *w[4], *bi[4], *bnw[4], *bnb[4], *bnm[4], *bnv[4];
    for (int br = 0; br < 4; ++br) {
        int base = 1 + br * 6;
        w[br]   = (const float*)d_in[base + 0];
        bi[br]  = (const float*)d_in[base + 1];
        bnw[br] = (const float*)d_in[base + 2];
        bnb[br] = (const float*)d_in[base + 3];
        bnm[br] = (const float*)d_in[base + 4];
        bnv[br] = (const float*)d_in[base + 5];
    }

    char* p = (char*)d_ws;
    double* pw = (double*)p;  p += 8 * 512 * sizeof(double);      // 32 KB
    u64* qm = (u64*)p;        p += 131072 * sizeof(u64);          // 1 MB
    u64* km = (u64*)p;        p += 131072 * sizeof(u64);          // 1 MB
    u64* vm = (u64*)p;        p += 131072 * sizeof(u64);          // 1 MB
    float* Y = (float*)p;     p += (size_t)16384 * 512 * 4;       // 33.5 MB
    float* r = (float*)d_out;  // retention spikes staged in d_out, consumed
                               // by the p-GEMM, then d_out fully rewritten.

    pow_kernel<<<1, 64, 0, stream>>>(pw);

    dim3 gg(256, 8);
    gemm_bn<<<gg, 256, 0, stream>>>(x, w[0], bi[0], bnw[0], bnb[0], bnm[0], bnv[0], Y);
    lif_mask<<<8192, TPB, 0, stream>>>(Y, qm);
    gemm_bn<<<gg, 256, 0, stream>>>(x, w[1], bi[1], bnw[1], bnb[1], bnm[1], bnv[1], Y);
    lif_mask<<<8192, TPB, 0, stream>>>(Y, km);
    gemm_bn<<<gg, 256, 0, stream>>>(x, w[2], bi[2], bnw[2], bnb[2], bnm[2], bnv[2], Y);
    lif_mask<<<8192, TPB, 0, stream>>>(Y, vm);

    retention5<<<1024, 512, 0, stream>>>(qm, km, vm, pw, r);

    gemm_bn<<<gg, 256, 0, stream>>>(r, w[3], bi[3], bnw[3], bnb[3], bnm[3], bnv[3], Y);
    final_lif<<<8192, TPB, 0, stream>>>(Y, (float*)d_out);
}

// Round 7
// 996.132 us; speedup vs baseline: 1.5505x; 1.2074x over previous
//
#include <hip/hip_runtime.h>
#include <cstdint>

typedef unsigned long long u64;

#define TPB 256

// ---------------------------------------------------------------------------
// gamma^dist table, fp64. pw[h*512 + dist]
__global__ void pow_kernel(double* __restrict__ pw) {
    int h = threadIdx.x;
    if (h < 8) {
        double gamma = 1.0 - ldexp(1.0, -5 - h);   // 1 - 2^-(5+h), exact
        double p = 1.0;
        for (int i = 0; i < 512; ++i) { pw[h * 512 + i] = p; p *= gamma; }
    }
}

// ---------------------------------------------------------------------------
// out[m,d] = BN( sum_c A[m,c]*W[d,c] + bias[d] ), fp64 accumulation, v2.
// 128x128 tile, 256 threads, 8x8 fp64 acc/thread, BK=16.
// LDS holds fp64 (converted once at staging); inner reads double2 (b128).
__global__ __launch_bounds__(256, 2) void gemm_bn2(
    const float* __restrict__ A, const float* __restrict__ W,
    const float* __restrict__ bias,
    const float* __restrict__ bnw, const float* __restrict__ bnb,
    const float* __restrict__ bnm, const float* __restrict__ bnv,
    float* __restrict__ out)
{
    const int K = 512;
    __shared__ double As[128][18];   // stride 18: 144B rows, 16B-aligned, <=2-way
    __shared__ double Ws[128][18];

    const int tid = threadIdx.x;
    const int m0 = blockIdx.x * 128;
    const int d0 = blockIdx.y * 128;
    const int srow = tid >> 1;            // 0..127
    const int scol = (tid & 1) << 3;      // 0 or 8
    const int tm = tid >> 4;              // 0..15
    const int td = tid & 15;              // 0..15

    double acc[8][8];
    #pragma unroll
    for (int i = 0; i < 8; ++i)
        #pragma unroll
        for (int j = 0; j < 8; ++j) acc[i][j] = 0.0;

    const float* ap = A + (size_t)(m0 + srow) * K + scol;
    const float* wp = W + (size_t)(d0 + srow) * K + scol;

    float4 pa0 = *(const float4*)(ap);
    float4 pa1 = *(const float4*)(ap + 4);
    float4 pw0 = *(const float4*)(wp);
    float4 pw1 = *(const float4*)(wp + 4);

    for (int k0 = 0; k0 < K; k0 += 16) {
        // stage (fp32 -> fp64 once)
        As[srow][scol + 0] = (double)pa0.x;
        As[srow][scol + 1] = (double)pa0.y;
        As[srow][scol + 2] = (double)pa0.z;
        As[srow][scol + 3] = (double)pa0.w;
        As[srow][scol + 4] = (double)pa1.x;
        As[srow][scol + 5] = (double)pa1.y;
        As[srow][scol + 6] = (double)pa1.z;
        As[srow][scol + 7] = (double)pa1.w;
        Ws[srow][scol + 0] = (double)pw0.x;
        Ws[srow][scol + 1] = (double)pw0.y;
        Ws[srow][scol + 2] = (double)pw0.z;
        Ws[srow][scol + 3] = (double)pw0.w;
        Ws[srow][scol + 4] = (double)pw1.x;
        Ws[srow][scol + 5] = (double)pw1.y;
        Ws[srow][scol + 6] = (double)pw1.z;
        Ws[srow][scol + 7] = (double)pw1.w;
        __syncthreads();

        if (k0 + 16 < K) {
            pa0 = *(const float4*)(ap + k0 + 16);
            pa1 = *(const float4*)(ap + k0 + 20);
            pw0 = *(const float4*)(wp + k0 + 16);
            pw1 = *(const float4*)(wp + k0 + 20);
        }

        #pragma unroll
        for (int kp = 0; kp < 8; ++kp) {
            double2 ad[8], wd[8];
            #pragma unroll
            for (int i = 0; i < 8; ++i)
                ad[i] = *(const double2*)&As[tm + 16 * i][kp * 2];
            #pragma unroll
            for (int j = 0; j < 8; ++j)
                wd[j] = *(const double2*)&Ws[td + 16 * j][kp * 2];
            #pragma unroll
            for (int i = 0; i < 8; ++i)
                #pragma unroll
                for (int j = 0; j < 8; ++j) {
                    acc[i][j] = fma(ad[i].x, wd[j].x, acc[i][j]);
                    acc[i][j] = fma(ad[i].y, wd[j].y, acc[i][j]);
                }
        }
        __syncthreads();
    }

    #pragma unroll
    for (int j = 0; j < 8; ++j) {
        int d = d0 + td + 16 * j;
        double inv = (double)bnw[d] / sqrt((double)bnv[d] + 1e-5);
        double sh  = (double)bnb[d] - (double)bnm[d] * inv;
        double bs  = (double)bias[d];
        #pragma unroll
        for (int i = 0; i < 8; ++i) {
            int m = m0 + tm + 16 * i;
            out[(size_t)m * 512 + d] = (float)((acc[i][j] + bs) * inv + sh);
        }
    }
}

// ---------------------------------------------------------------------------
// LIF (v_th=1.0) over T=4 on Y; pack spikes into per-(t,b,h,n) 64-bit masks.
__global__ void lif_mask(const float* __restrict__ Y, u64* __restrict__ msk) {
    int g = blockIdx.x * TPB + threadIdx.x;
    int c = g & 511, n = (g >> 9) & 511, b = g >> 18;
    int h = c >> 6;
    int lane = threadIdx.x & 63;
    double v = 0.0;
    for (int t = 0; t < 4; ++t) {
        float y = Y[((size_t)((t * 8 + b) * 512 + n) << 9) + c];
        double hh = v + ((double)y - v) * 0.5;
        bool s = hh >= 1.0;
        u64 mk = __ballot(s);
        if (lane == 0) msk[((t * 8 + b) * 8 + h) * 512 + n] = mk;
        v = s ? 0.0 : hh;
    }
}

// ---------------------------------------------------------------------------
// Retention + retention LIF, v6 (= v5 with NMASK retuned 14->6, unroll 4).
// Measured R6: mask path ~20cy/d, SGPR path 4cy/d + 2 SALU/d; balance at
// f = 26/32 -> SALU demand ~0.82/cy/CU.
#define NMASK 6
__global__ __launch_bounds__(512) void retention6(
    const u64* __restrict__ qm, const u64* __restrict__ km,
    const u64* __restrict__ vm, const double* __restrict__ pw,
    float* __restrict__ r)
{
    int bid = blockIdx.x;            // 1024 = b(8)*h(8)*ng(8)*dh(2)
    int dh = bid & 1;
    int ng = (bid >> 1) & 7;
    int h  = (bid >> 4) & 7;
    int b  = bid >> 7;
    int wid  = threadIdx.x >> 6;     // 0..7
    int t    = wid & 3;
    int mh   = wid >> 2;             // m-half
    int lane = threadIdx.x & 63;
    int n = ng * 64 + lane;

    __shared__ double pw_s[512];            // 4 KB
    __shared__ double comb[4][64][17];      // 34 KB combine buffer (padded)
    double* vs_s = &comb[0][0][0];          // reused for LIF vstate

    if (threadIdx.x < 512) pw_s[threadIdx.x] = pw[h * 512 + threadIdx.x];
    __syncthreads();

    int base = ((t * 8 + b) * 8 + h) * 512;
    u64 qn = qm[base + n];
    const u64* kp = km + base + mh * 256;
    const u64* vp = vm + base + mh * 256;
    int msta = mh * 256;

    double acc[32];
    #pragma unroll
    for (int dd = 0; dd < 32; ++dd) acc[dd] = 0.0;

    u64 kcur = kp[lane];
    u64 vcur = vp[lane];
    #pragma unroll 1
    for (int c = 0; c < 4; ++c) {
        u64 knxt = 0, vnxt = 0;
        if (c < 3) {
            knxt = kp[(c + 1) * 64 + lane];
            vnxt = vp[(c + 1) * 64 + lane];
        }
        // the 32 v-bits this block needs live in one 32-bit word (dh picks it)
        unsigned vsel = dh ? (unsigned)(vcur >> 32) : (unsigned)vcur;
        int mbase = msta + c * 64;
        #pragma unroll 4
        for (int mm = 0; mm < 64; ++mm) {
            unsigned kl = __builtin_amdgcn_readlane((unsigned)kcur, mm);
            unsigned kh = __builtin_amdgcn_readlane((unsigned)(kcur >> 32), mm);
            unsigned vv_s = __builtin_amdgcn_readlane(vsel, mm);   // SGPR
            u64 kv = ((u64)kh << 32) | kl;
            int m = mbase + mm;
            int dist = n - m; if (dist < 0) dist = -dist;
            double w = (double)__popcll(qn & kv) * pw_s[dist];
            u64 wbits = __builtin_bit_cast(u64, w);

            // VALU-mask path: launder vv into a VGPR so it can't scalarize
            unsigned vv_v;
            asm("v_mov_b32 %0, %1" : "=v"(vv_v) : "s"(vv_s));
            #pragma unroll
            for (int dd = 0; dd < NMASK; ++dd) {
                unsigned mk = (unsigned)(((int)(vv_v << (31 - dd))) >> 31);
                u64 gw = (((u64)mk << 32) | mk) & wbits;
                acc[dd] += __builtin_bit_cast(double, gw);
            }
            // SALU-select path
            #pragma unroll
            for (int dd = NMASK; dd < 32; ++dd)
                acc[dd] = fma(w, ((vv_s >> dd) & 1u) ? 1.0 : 0.0, acc[dd]);
        }
        kcur = knxt; vcur = vnxt;
    }

    // ---- combine m-halves (fixed order: acc(mh0) + acc(mh1)), 16 d at a time
    __syncthreads();
    if (mh == 1) {
        #pragma unroll
        for (int dd = 0; dd < 16; ++dd) comb[t][lane][dd] = acc[dd];
    }
    __syncthreads();
    if (mh == 0) {
        #pragma unroll
        for (int dd = 0; dd < 16; ++dd) acc[dd] += comb[t][lane][dd];
    }
    __syncthreads();
    if (mh == 1) {
        #pragma unroll
        for (int dd = 16; dd < 32; ++dd) comb[t][lane][dd - 16] = acc[dd];
    }
    __syncthreads();
    if (mh == 0) {
        #pragma unroll
        for (int dd = 16; dd < 32; ++dd) acc[dd] += comb[t][lane][dd - 16];
    }
    __syncthreads();

    // ---- LIF chain across t (v_th=0.5, hard reset); vstate via reused LDS
    for (int tt = 0; tt < 4; ++tt) {
        if (tt == t && mh == 0) {
            size_t rbase = ((size_t)((t * 8 + b) * 512 + n) << 9) + h * 64 + dh * 32;
            #pragma unroll
            for (int dd = 0; dd < 32; ++dd) {
                int sw = lane * 33 + dd;
                double v = (t == 0) ? 0.0 : vs_s[sw];
                double x = acc[dd] * 0.125;
                double hh = v + (x - v) * 0.5;
                bool s = hh >= 0.5;
                r[rbase + dd] = s ? 1.0f : 0.0f;
                if (t < 3) vs_s[sw] = s ? 0.0 : hh;
            }
        }
        __syncthreads();
    }
}

// ---------------------------------------------------------------------------
// Final LIF (v_th=1.0) over T on Y; writes {0,1} fp32 to out.
__global__ void final_lif(const float* __restrict__ Y, float* __restrict__ out) {
    int g = blockIdx.x * TPB + threadIdx.x;
    int c = g & 511, n = (g >> 9) & 511, b = g >> 18;
    double v = 0.0;
    for (int t = 0; t < 4; ++t) {
        size_t idx = ((size_t)((t * 8 + b) * 512 + n) << 9) + c;
        float y = Y[idx];
        double hh = v + ((double)y - v) * 0.5;
        bool s = hh >= 1.0;
        out[idx] = s ? 1.0f : 0.0f;
        v = s ? 0.0 : hh;
    }
}

// ---------------------------------------------------------------------------
extern "C" void kernel_launch(void* const* d_in, const int* in_sizes, int n_in,
                              void* d_out, int out_size, void* d_ws, size_t ws_size,
                              hipStream_t stream) {
    const float* x = (const float*)d_in[0];
    const float *w[4], *bi[4], *bnw[4], *bnb[4], *bnm[4], *bnv[4];
    for (int br = 0; br < 4; ++br) {
        int base = 1 + br * 6;
        w[br]   = (const float*)d_in[base + 0];
        bi[br]  = (const float*)d_in[base + 1];
        bnw[br] = (const float*)d_in[base + 2];
        bnb[br] = (const float*)d_in[base + 3];
        bnm[br] = (const float*)d_in[base + 4];
        bnv[br] = (const float*)d_in[base + 5];
    }

    char* p = (char*)d_ws;
    double* pw = (double*)p;  p += 8 * 512 * sizeof(double);      // 32 KB
    u64* qm = (u64*)p;        p += 131072 * sizeof(u64);          // 1 MB
    u64* km = (u64*)p;        p += 131072 * sizeof(u64);          // 1 MB
    u64* vm = (u64*)p;        p += 131072 * sizeof(u64);          // 1 MB
    float* Y = (float*)p;     p += (size_t)16384 * 512 * 4;       // 33.5 MB
    float* r = (float*)d_out;  // retention spikes staged in d_out, consumed
                               // by the p-GEMM, then d_out fully rewritten.

    pow_kernel<<<1, 64, 0, stream>>>(pw);

    dim3 gg(128, 4);
    gemm_bn2<<<gg, 256, 0, stream>>>(x, w[0], bi[0], bnw[0], bnb[0], bnm[0], bnv[0], Y);
    lif_mask<<<8192, TPB, 0, stream>>>(Y, qm);
    gemm_bn2<<<gg, 256, 0, stream>>>(x, w[1], bi[1], bnw[1], bnb[1], bnm[1], bnv[1], Y);
    lif_mask<<<8192, TPB, 0, stream>>>(Y, km);
    gemm_bn2<<<gg, 256, 0, stream>>>(x, w[2], bi[2], bnw[2], bnb[2], bnm[2], bnv[2], Y);
    lif_mask<<<8192, TPB, 0, stream>>>(Y, vm);

    retention6<<<1024, 512, 0, stream>>>(qm, km, vm, pw, r);

    gemm_bn2<<<gg, 256, 0, stream>>>(r, w[3], bi[3], bnw[3], bnb[3], bnm[3], bnv[3], Y);
    final_lif<<<8192, TPB, 0, stream>>>(Y, (float*)d_out);
}

// Round 8
// 876.312 us; speedup vs baseline: 1.7625x; 1.1367x over previous
//
#include <hip/hip_runtime.h>
#include <cstdint>

typedef unsigned long long u64;

#define TPB 256
#define MARGIN 5e-4
#define FCAP (1 << 20)

// ---------------------------------------------------------------------------
// gamma^dist table, fp64. pw[h*512 + dist]
__global__ void pow_kernel(double* __restrict__ pw) {
    int h = threadIdx.x;
    if (h < 8) {
        double gamma = 1.0 - ldexp(1.0, -5 - h);   // 1 - 2^-(5+h), exact
        double p = 1.0;
        for (int i = 0; i < 512; ++i) { pw[h * 512 + i] = p; p *= gamma; }
    }
}

__global__ void zero_counters(int* __restrict__ ctr) {
    if (threadIdx.x < 4) ctr[threadIdx.x] = 0;
}

// ---------------------------------------------------------------------------
// fp32 GEMM + BN: out[m,d] = BN( sum_c A[m,c]*W[d,c] + bias[d] ).
// 128x128 tile, 256 threads, 8x8 fp32 acc/thread, BK=16. Epilogue BN in fp64.
__global__ __launch_bounds__(256, 2) void gemm_bn_f32(
    const float* __restrict__ A, const float* __restrict__ W,
    const float* __restrict__ bias,
    const float* __restrict__ bnw, const float* __restrict__ bnb,
    const float* __restrict__ bnm, const float* __restrict__ bnv,
    float* __restrict__ out)
{
    const int K = 512;
    __shared__ float As[128][20];   // pad 20: 80B rows (16B-aligned), reads conflict-free/2-way
    __shared__ float Ws[128][20];

    const int tid = threadIdx.x;
    const int m0 = blockIdx.x * 128;
    const int d0 = blockIdx.y * 128;
    const int srow = tid >> 1;            // 0..127
    const int scol = (tid & 1) << 3;      // 0 or 8
    const int tm = tid >> 4;              // 0..15
    const int td = tid & 15;              // 0..15

    float acc[8][8];
    #pragma unroll
    for (int i = 0; i < 8; ++i)
        #pragma unroll
        for (int j = 0; j < 8; ++j) acc[i][j] = 0.0f;

    const float* ap = A + (size_t)(m0 + srow) * K + scol;
    const float* wp = W + (size_t)(d0 + srow) * K + scol;

    float4 pa0 = *(const float4*)(ap);
    float4 pa1 = *(const float4*)(ap + 4);
    float4 pw0 = *(const float4*)(wp);
    float4 pw1 = *(const float4*)(wp + 4);

    for (int k0 = 0; k0 < K; k0 += 16) {
        *(float4*)&As[srow][scol]     = pa0;
        *(float4*)&As[srow][scol + 4] = pa1;
        *(float4*)&Ws[srow][scol]     = pw0;
        *(float4*)&Ws[srow][scol + 4] = pw1;
        __syncthreads();

        if (k0 + 16 < K) {
            pa0 = *(const float4*)(ap + k0 + 16);
            pa1 = *(const float4*)(ap + k0 + 20);
            pw0 = *(const float4*)(wp + k0 + 16);
            pw1 = *(const float4*)(wp + k0 + 20);
        }

        #pragma unroll
        for (int kg = 0; kg < 4; ++kg) {
            float4 av[8], wv[8];
            #pragma unroll
            for (int i = 0; i < 8; ++i)
                av[i] = *(const float4*)&As[tm + 16 * i][kg * 4];
            #pragma unroll
            for (int j = 0; j < 8; ++j)
                wv[j] = *(const float4*)&Ws[td + 16 * j][kg * 4];
            #pragma unroll
            for (int i = 0; i < 8; ++i)
                #pragma unroll
                for (int j = 0; j < 8; ++j) {
                    acc[i][j] = fmaf(av[i].x, wv[j].x, acc[i][j]);
                    acc[i][j] = fmaf(av[i].y, wv[j].y, acc[i][j]);
                    acc[i][j] = fmaf(av[i].z, wv[j].z, acc[i][j]);
                    acc[i][j] = fmaf(av[i].w, wv[j].w, acc[i][j]);
                }
        }
        __syncthreads();
    }

    #pragma unroll
    for (int j = 0; j < 8; ++j) {
        int d = d0 + td + 16 * j;
        double inv = (double)bnw[d] / sqrt((double)bnv[d] + 1e-5);
        double sh  = (double)bnb[d] - (double)bnm[d] * inv;
        double bs  = (double)bias[d];
        #pragma unroll
        for (int i = 0; i < 8; ++i) {
            int m = m0 + tm + 16 * i;
            out[(size_t)m * 512 + d] = (float)(((double)acc[i][j] + bs) * inv + sh);
        }
    }
}

// ---------------------------------------------------------------------------
// LIF (v_th=1.0) over T=4 on Y; pack spikes into per-(t,b,h,n) masks; flag
// any neuron whose h comes within MARGIN of threshold (exact fp64 repair later).
__global__ void lif_mask_flag(const float* __restrict__ Y, u64* __restrict__ msk,
                              int* __restrict__ ctr, int* __restrict__ list, int slot) {
    int g = blockIdx.x * TPB + threadIdx.x;
    int c = g & 511, n = (g >> 9) & 511, b = g >> 18;
    int h = c >> 6;
    int lane = threadIdx.x & 63;
    double v = 0.0;
    bool flag = false;
    for (int t = 0; t < 4; ++t) {
        float y = Y[((size_t)((t * 8 + b) * 512 + n) << 9) + c];
        double hh = v + ((double)y - v) * 0.5;
        flag |= fabs(hh - 1.0) < MARGIN;
        bool s = hh >= 1.0;
        u64 mk = __ballot(s);
        if (lane == 0) msk[((t * 8 + b) * 8 + h) * 512 + n] = mk;
        v = s ? 0.0 : hh;
    }
    if (flag) {
        int idx = atomicAdd(ctr + slot, 1);
        if (idx < FCAP) list[idx] = g;
    }
}

// ---------------------------------------------------------------------------
// Exact fp64 repair of flagged neurons: recompute dot, BN, LIF; fix mask bits.
__global__ void fix_mask(const float* __restrict__ x, const float* __restrict__ w,
                         const float* __restrict__ bias,
                         const float* __restrict__ bnw, const float* __restrict__ bnb,
                         const float* __restrict__ bnm, const float* __restrict__ bnv,
                         u64* __restrict__ msk, const int* __restrict__ ctr,
                         const int* __restrict__ list, int slot) {
    int cnt = ctr[slot]; if (cnt > FCAP) cnt = FCAP;
    int wv = (blockIdx.x * blockDim.x + threadIdx.x) >> 6;
    int nw = (gridDim.x * blockDim.x) >> 6;
    int lane = threadIdx.x & 63;
    for (int i = wv; i < cnt; i += nw) {
        int g = list[i];
        int c = g & 511, n = (g >> 9) & 511, b = g >> 18;
        int h = c >> 6;
        const float* wr = w + (size_t)c * 512;
        double dot[4];
        #pragma unroll
        for (int t = 0; t < 4; ++t) {
            const float* xr = x + ((size_t)((t * 8 + b) * 512 + n) << 9);
            double p = 0.0;
            #pragma unroll
            for (int j = 0; j < 8; ++j)
                p += (double)xr[lane + 64 * j] * (double)wr[lane + 64 * j];
            dot[t] = p;
        }
        #pragma unroll
        for (int off = 32; off; off >>= 1) {
            #pragma unroll
            for (int t = 0; t < 4; ++t)
                dot[t] += __shfl_xor(dot[t], off, 64);
        }
        if (lane == 0) {
            double inv = (double)bnw[c] / sqrt((double)bnv[c] + 1e-5);
            double sh  = (double)bnb[c] - (double)bnm[c] * inv;
            double bs  = (double)bias[c];
            double v = 0.0;
            u64 bit = 1ull << (c & 63);
            for (int t = 0; t < 4; ++t) {
                double y = (dot[t] + bs) * inv + sh;
                double hh = v + (y - v) * 0.5;
                bool s = hh >= 1.0;
                u64* wp_ = &msk[((t * 8 + b) * 8 + h) * 512 + n];
                if (s) atomicOr(wp_, bit); else atomicAnd(wp_, ~bit);
                v = s ? 0.0 : hh;
            }
        }
    }
}

// ---------------------------------------------------------------------------
// Retention + retention LIF (exact fp64), NMASK=6 (R7-tuned).
#define NMASK 6
__global__ __launch_bounds__(512) void retention6(
    const u64* __restrict__ qm, const u64* __restrict__ km,
    const u64* __restrict__ vm, const double* __restrict__ pw,
    float* __restrict__ r)
{
    int bid = blockIdx.x;            // 1024 = b(8)*h(8)*ng(8)*dh(2)
    int dh = bid & 1;
    int ng = (bid >> 1) & 7;
    int h  = (bid >> 4) & 7;
    int b  = bid >> 7;
    int wid  = threadIdx.x >> 6;     // 0..7
    int t    = wid & 3;
    int mh   = wid >> 2;             // m-half
    int lane = threadIdx.x & 63;
    int n = ng * 64 + lane;

    __shared__ double pw_s[512];
    __shared__ double comb[4][64][17];
    double* vs_s = &comb[0][0][0];

    if (threadIdx.x < 512) pw_s[threadIdx.x] = pw[h * 512 + threadIdx.x];
    __syncthreads();

    int base = ((t * 8 + b) * 8 + h) * 512;
    u64 qn = qm[base + n];
    const u64* kp = km + base + mh * 256;
    const u64* vp = vm + base + mh * 256;
    int msta = mh * 256;

    double acc[32];
    #pragma unroll
    for (int dd = 0; dd < 32; ++dd) acc[dd] = 0.0;

    u64 kcur = kp[lane];
    u64 vcur = vp[lane];
    #pragma unroll 1
    for (int c = 0; c < 4; ++c) {
        u64 knxt = 0, vnxt = 0;
        if (c < 3) {
            knxt = kp[(c + 1) * 64 + lane];
            vnxt = vp[(c + 1) * 64 + lane];
        }
        unsigned vsel = dh ? (unsigned)(vcur >> 32) : (unsigned)vcur;
        int mbase = msta + c * 64;
        #pragma unroll 4
        for (int mm = 0; mm < 64; ++mm) {
            unsigned kl = __builtin_amdgcn_readlane((unsigned)kcur, mm);
            unsigned kh = __builtin_amdgcn_readlane((unsigned)(kcur >> 32), mm);
            unsigned vv_s = __builtin_amdgcn_readlane(vsel, mm);   // SGPR
            u64 kv = ((u64)kh << 32) | kl;
            int m = mbase + mm;
            int dist = n - m; if (dist < 0) dist = -dist;
            double w = (double)__popcll(qn & kv) * pw_s[dist];
            u64 wbits = __builtin_bit_cast(u64, w);

            unsigned vv_v;
            asm("v_mov_b32 %0, %1" : "=v"(vv_v) : "s"(vv_s));
            #pragma unroll
            for (int dd = 0; dd < NMASK; ++dd) {
                unsigned mk = (unsigned)(((int)(vv_v << (31 - dd))) >> 31);
                u64 gw = (((u64)mk << 32) | mk) & wbits;
                acc[dd] += __builtin_bit_cast(double, gw);
            }
            #pragma unroll
            for (int dd = NMASK; dd < 32; ++dd)
                acc[dd] = fma(w, ((vv_s >> dd) & 1u) ? 1.0 : 0.0, acc[dd]);
        }
        kcur = knxt; vcur = vnxt;
    }

    __syncthreads();
    if (mh == 1) {
        #pragma unroll
        for (int dd = 0; dd < 16; ++dd) comb[t][lane][dd] = acc[dd];
    }
    __syncthreads();
    if (mh == 0) {
        #pragma unroll
        for (int dd = 0; dd < 16; ++dd) acc[dd] += comb[t][lane][dd];
    }
    __syncthreads();
    if (mh == 1) {
        #pragma unroll
        for (int dd = 16; dd < 32; ++dd) comb[t][lane][dd - 16] = acc[dd];
    }
    __syncthreads();
    if (mh == 0) {
        #pragma unroll
        for (int dd = 16; dd < 32; ++dd) acc[dd] += comb[t][lane][dd - 16];
    }
    __syncthreads();

    for (int tt = 0; tt < 4; ++tt) {
        if (tt == t && mh == 0) {
            size_t rbase = ((size_t)((t * 8 + b) * 512 + n) << 9) + h * 64 + dh * 32;
            #pragma unroll
            for (int dd = 0; dd < 32; ++dd) {
                int sw = lane * 33 + dd;
                double v = (t == 0) ? 0.0 : vs_s[sw];
                double x = acc[dd] * 0.125;
                double hh = v + (x - v) * 0.5;
                bool s = hh >= 0.5;
                r[rbase + dd] = s ? 1.0f : 0.0f;
                if (t < 3) vs_s[sw] = s ? 0.0 : hh;
            }
        }
        __syncthreads();
    }
}

// ---------------------------------------------------------------------------
// Final-branch flag pass (no writes to d_out; r in d_out stays intact).
__global__ void final_flag(const float* __restrict__ Y, int* __restrict__ ctr,
                           int* __restrict__ list) {
    int g = blockIdx.x * TPB + threadIdx.x;
    int c = g & 511, n = (g >> 9) & 511, b = g >> 18;
    double v = 0.0;
    bool flag = false;
    for (int t = 0; t < 4; ++t) {
        float y = Y[((size_t)((t * 8 + b) * 512 + n) << 9) + c];
        double hh = v + ((double)y - v) * 0.5;
        flag |= fabs(hh - 1.0) < MARGIN;
        bool s = hh >= 1.0;
        v = s ? 0.0 : hh;
    }
    if (flag) {
        int idx = atomicAdd(ctr + 3, 1);
        if (idx < FCAP) list[idx] = g;
    }
}

// Exact fp64 recompute for flagged final neurons; spikes packed into list[i] bits 24..27.
__global__ void fix_final(const float* __restrict__ rr, const float* __restrict__ w,
                          const float* __restrict__ bias,
                          const float* __restrict__ bnw, const float* __restrict__ bnb,
                          const float* __restrict__ bnm, const float* __restrict__ bnv,
                          const int* __restrict__ ctr, int* __restrict__ list) {
    int cnt = ctr[3]; if (cnt > FCAP) cnt = FCAP;
    int wv = (blockIdx.x * blockDim.x + threadIdx.x) >> 6;
    int nw = (gridDim.x * blockDim.x) >> 6;
    int lane = threadIdx.x & 63;
    for (int i = wv; i < cnt; i += nw) {
        int g = list[i] & 0x00FFFFFF;
        int c = g & 511, n = (g >> 9) & 511, b = g >> 18;
        const float* wr = w + (size_t)c * 512;
        double dot[4];
        #pragma unroll
        for (int t = 0; t < 4; ++t) {
            const float* xr = rr + ((size_t)((t * 8 + b) * 512 + n) << 9);
            double p = 0.0;
            #pragma unroll
            for (int j = 0; j < 8; ++j)
                p += (double)xr[lane + 64 * j] * (double)wr[lane + 64 * j];
            dot[t] = p;
        }
        #pragma unroll
        for (int off = 32; off; off >>= 1) {
            #pragma unroll
            for (int t = 0; t < 4; ++t)
                dot[t] += __shfl_xor(dot[t], off, 64);
        }
        if (lane == 0) {
            double inv = (double)bnw[c] / sqrt((double)bnv[c] + 1e-5);
            double sh  = (double)bnb[c] - (double)bnm[c] * inv;
            double bs  = (double)bias[c];
            double v = 0.0;
            int sp = 0;
            for (int t = 0; t < 4; ++t) {
                double y = (dot[t] + bs) * inv + sh;
                double hh = v + (y - v) * 0.5;
                bool s = hh >= 1.0;
                sp |= (s ? 1 : 0) << t;
                v = s ? 0.0 : hh;
            }
            list[i] = g | (sp << 24);
        }
    }
}

// Provisional final LIF write (overwrites d_out = r).
__global__ void final_write(const float* __restrict__ Y, float* __restrict__ out) {
    int g = blockIdx.x * TPB + threadIdx.x;
    int c = g & 511, n = (g >> 9) & 511, b = g >> 18;
    double v = 0.0;
    for (int t = 0; t < 4; ++t) {
        size_t idx = ((size_t)((t * 8 + b) * 512 + n) << 9) + c;
        float y = Y[idx];
        double hh = v + ((double)y - v) * 0.5;
        bool s = hh >= 1.0;
        out[idx] = s ? 1.0f : 0.0f;
        v = s ? 0.0 : hh;
    }
}

// Scatter exact spikes for flagged final neurons.
__global__ void fix_scatter(const int* __restrict__ ctr, const int* __restrict__ list,
                            float* __restrict__ out) {
    int cnt = ctr[3]; if (cnt > FCAP) cnt = FCAP;
    int i = blockIdx.x * blockDim.x + threadIdx.x;
    if (i >= cnt) return;
    int e = list[i];
    int g = e & 0x00FFFFFF, sp = (e >> 24) & 0xF;
    int c = g & 511, n = (g >> 9) & 511, b = g >> 18;
    for (int t = 0; t < 4; ++t)
        out[((size_t)((t * 8 + b) * 512 + n) << 9) + c] = ((sp >> t) & 1) ? 1.0f : 0.0f;
}

// ---------------------------------------------------------------------------
extern "C" void kernel_launch(void* const* d_in, const int* in_sizes, int n_in,
                              void* d_out, int out_size, void* d_ws, size_t ws_size,
                              hipStream_t stream) {
    const float* x = (const float*)d_in[0];
    const float *w[4], *bi[4], *bnw[4], *bnb[4], *bnm[4], *bnv[4];
    for (int br = 0; br < 4; ++br) {
        int base = 1 + br * 6;
        w[br]   = (const float*)d_in[base + 0];
        bi[br]  = (const float*)d_in[base + 1];
        bnw[br] = (const float*)d_in[base + 2];
        bnb[br] = (const float*)d_in[base + 3];
        bnm[br] = (const float*)d_in[base + 4];
        bnv[br] = (const float*)d_in[base + 5];
    }

    char* p = (char*)d_ws;
    double* pw = (double*)p;  p += 8 * 512 * sizeof(double);      // 32 KB
    u64* qm = (u64*)p;        p += 131072 * sizeof(u64);          // 1 MB
    u64* km = (u64*)p;        p += 131072 * sizeof(u64);          // 1 MB
    u64* vm = (u64*)p;        p += 131072 * sizeof(u64);          // 1 MB
    int* ctr = (int*)p;       p += 1024;                          // 4 counters
    int* list = (int*)p;      p += (size_t)FCAP * sizeof(int);    // 4 MB
    float* Y = (float*)p;     p += (size_t)16384 * 512 * 4;       // 33.5 MB
    float* r = (float*)d_out;  // retention spikes staged in d_out

    zero_counters<<<1, 64, 0, stream>>>(ctr);
    pow_kernel<<<1, 64, 0, stream>>>(pw);

    dim3 gg(128, 4);
    // q
    gemm_bn_f32<<<gg, 256, 0, stream>>>(x, w[0], bi[0], bnw[0], bnb[0], bnm[0], bnv[0], Y);
    lif_mask_flag<<<8192, TPB, 0, stream>>>(Y, qm, ctr, list, 0);
    fix_mask<<<128, 256, 0, stream>>>(x, w[0], bi[0], bnw[0], bnb[0], bnm[0], bnv[0], qm, ctr, list, 0);
    // k
    gemm_bn_f32<<<gg, 256, 0, stream>>>(x, w[1], bi[1], bnw[1], bnb[1], bnm[1], bnv[1], Y);
    lif_mask_flag<<<8192, TPB, 0, stream>>>(Y, km, ctr, list, 1);
    fix_mask<<<128, 256, 0, stream>>>(x, w[1], bi[1], bnw[1], bnb[1], bnm[1], bnv[1], km, ctr, list, 1);
    // v
    gemm_bn_f32<<<gg, 256, 0, stream>>>(x, w[2], bi[2], bnw[2], bnb[2], bnm[2], bnv[2], Y);
    lif_mask_flag<<<8192, TPB, 0, stream>>>(Y, vm, ctr, list, 2);
    fix_mask<<<128, 256, 0, stream>>>(x, w[2], bi[2], bnw[2], bnb[2], bnm[2], bnv[2], vm, ctr, list, 2);

    // retention (exact) -> r in d_out
    retention6<<<1024, 512, 0, stream>>>(qm, km, vm, pw, r);

    // p projection (fp32) + flag/fix/write/scatter
    gemm_bn_f32<<<gg, 256, 0, stream>>>(r, w[3], bi[3], bnw[3], bnb[3], bnm[3], bnv[3], Y);
    final_flag<<<8192, TPB, 0, stream>>>(Y, ctr, list);
    fix_final<<<128, 256, 0, stream>>>(r, w[3], bi[3], bnw[3], bnb[3], bnm[3], bnv[3], ctr, list);
    final_write<<<8192, TPB, 0, stream>>>(Y, (float*)d_out);
    fix_scatter<<<4096, 256, 0, stream>>>(ctr, list, (float*)d_out);
}